// Round 1
// baseline (464.282 us; speedup 1.0000x reference)
//
#include <hip/hip_runtime.h>
#include <stdint.h>

#define HID 1024
#define NSEQ 1024
#define KREL 1024
#define NHEAD 16
#define DHEAD 64

typedef __attribute__((ext_vector_type(8))) short bhalf8;
typedef __attribute__((ext_vector_type(4))) float floatx4;

__device__ inline float bf2f(uint32_t hi) {
  union { uint32_t u; float f; } c; c.u = hi; return c.f;
}
__device__ inline uint16_t f2bf(float f) {
  union { float f; uint32_t u; } c; c.f = f;
  uint32_t u = c.u;
  return (uint16_t)((u + 0x7fffu + ((u >> 16) & 1u)) >> 16);
}

#define DOT4(a, b) ((a).x*(b).x + (a).y*(b).y + (a).z*(b).z + (a).w*(b).w)

// ---------------- fp32 -> bf16 cast ----------------
__global__ __launch_bounds__(256) void cast_kernel(const float* __restrict__ src,
                                                   uint16_t* __restrict__ dst, int n) {
  int idx = (blockIdx.x * 256 + threadIdx.x) * 4;
  if (idx + 3 < n) {
    float4 v = *(const float4*)(src + idx);
    ushort4 o;
    o.x = f2bf(v.x); o.y = f2bf(v.y); o.z = f2bf(v.z); o.w = f2bf(v.w);
    *(ushort4*)(dst + idx) = o;
  }
}

// ---------------- bf16 MFMA GEMM: C = A @ W^T + bias ----------------
// A: (M x 1024) bf16 row-major, W: (1024 x 1024) bf16 row-major (we use rows of W = cols of W^T)
// grid: (M/64, 16); block 256 = 4 waves in 2x2, each wave 32x32 via 2x2 MFMA 16x16x32 subtiles.
__global__ __launch_bounds__(256) void gemm_kernel(const uint16_t* __restrict__ A,
                                                   const uint16_t* __restrict__ Wt,
                                                   const float* __restrict__ bias,
                                                   void* __restrict__ C, int out_bf16) {
  __shared__ uint16_t a_s[64 * 40];  // pad 32->40 bf16 (80B rows, 16B aligned, 2-way max)
  __shared__ uint16_t b_s[64 * 40];
  int t = threadIdx.x;
  int i0 = blockIdx.x * 64;
  int n0 = blockIdx.y * 64;
  int lane = t & 63, w = t >> 6;
  int wm = (w >> 1) * 32, wn = (w & 1) * 32;
  int fr = lane & 15;          // m (or n) within 16x16 subtile
  int kg = (lane >> 4) * 8;    // k-offset of this lane's 8 contiguous elements

  int r = t >> 2, ch = (t & 3) * 8;  // staging: 64 rows x 4 chunks of 8 bf16
  const uint16_t* Arow = A + (size_t)(i0 + r) * HID + ch;
  const uint16_t* Brow = Wt + (size_t)(n0 + r) * HID + ch;
  uint16_t* as_dst = a_s + r * 40 + ch;
  uint16_t* bs_dst = b_s + r * 40 + ch;

  floatx4 acc00 = {0,0,0,0}, acc01 = {0,0,0,0}, acc10 = {0,0,0,0}, acc11 = {0,0,0,0};

  for (int kt = 0; kt < HID; kt += 32) {
    __syncthreads();
    *(uint4*)as_dst = *(const uint4*)(Arow + kt);
    *(uint4*)bs_dst = *(const uint4*)(Brow + kt);
    __syncthreads();
    bhalf8 a0 = *(bhalf8*)(a_s + (wm + fr) * 40 + kg);
    bhalf8 a1 = *(bhalf8*)(a_s + (wm + 16 + fr) * 40 + kg);
    bhalf8 b0 = *(bhalf8*)(b_s + (wn + fr) * 40 + kg);
    bhalf8 b1 = *(bhalf8*)(b_s + (wn + 16 + fr) * 40 + kg);
    acc00 = __builtin_amdgcn_mfma_f32_16x16x32_bf16(a0, b0, acc00, 0, 0, 0);
    acc01 = __builtin_amdgcn_mfma_f32_16x16x32_bf16(a0, b1, acc01, 0, 0, 0);
    acc10 = __builtin_amdgcn_mfma_f32_16x16x32_bf16(a1, b0, acc10, 0, 0, 0);
    acc11 = __builtin_amdgcn_mfma_f32_16x16x32_bf16(a1, b1, acc11, 0, 0, 0);
  }

  int rb0 = (lane >> 4) * 4;
  int cb0 = lane & 15;
#define EPI(ACC, SM, SN)                                                         \
  {                                                                              \
    int rowb = i0 + wm + (SM)*16 + rb0;                                          \
    int col = n0 + wn + (SN)*16 + cb0;                                           \
    float bv_ = bias[col];                                                       \
    _Pragma("unroll")                                                            \
    for (int rr = 0; rr < 4; ++rr) {                                             \
      float val = ACC[rr] + bv_;                                                 \
      if (out_bf16)                                                              \
        ((uint16_t*)C)[(size_t)(rowb + rr) * HID + col] = f2bf(val);             \
      else                                                                       \
        ((float*)C)[(size_t)(rowb + rr) * HID + col] = val;                      \
    }                                                                            \
  }
  EPI(acc00, 0, 0) EPI(acc01, 0, 1) EPI(acc10, 1, 0) EPI(acc11, 1, 1)
#undef EPI
}

// ---------------- staging helper: bf16 global (row stride HID) -> fp32 LDS ----------------
__device__ inline void stage_tile(float* dst, int ldd, const uint16_t* src, int rows, int t) {
  int total = rows * 8;  // 8 chunks of 8 bf16 per 64-col row
  for (int c = t; c < total; c += 256) {
    int r = c >> 3, ch = (c & 7) * 8;
    uint4 u = *(const uint4*)(src + (size_t)r * HID + ch);
    float* d = dst + r * ldd + ch;
    float4 f0, f1;
    f0.x = bf2f(u.x << 16); f0.y = bf2f(u.x & 0xffff0000u);
    f0.z = bf2f(u.y << 16); f0.w = bf2f(u.y & 0xffff0000u);
    f1.x = bf2f(u.z << 16); f1.y = bf2f(u.z & 0xffff0000u);
    f1.z = bf2f(u.w << 16); f1.w = bf2f(u.w & 0xffff0000u);
    *(float4*)d = f0;
    *(float4*)(d + 4) = f1;
  }
}

// ---------------- fused attention ----------------
// scores[h,i,j] = (q_i.k_j + q_i.pos_k[K+i-j] + k_j.pos_q[K+i-j]) / sqrt(192)
// block = (32 q-rows, 1 head); j-tiles of 32; online softmax; ctx written as bf16 (N,HID).
__global__ __launch_bounds__(256) void attn_kernel(const uint16_t* __restrict__ qg,
                                                   const uint16_t* __restrict__ kg,
                                                   const uint16_t* __restrict__ vg,
                                                   const uint16_t* __restrict__ pkg,
                                                   const uint16_t* __restrict__ pqg,
                                                   uint16_t* __restrict__ ctx) {
  const int TI = 32, TJ = 32, WIN = TI + TJ - 1;  // 63-row pos window
  const float RSCALE = 0.07216878364870323f;      // 1/sqrt(192)
  __shared__ float q_s[32][68];
  __shared__ float k_s[32][68];
  __shared__ float v_s[32][64];
  __shared__ float pk_s[63][68];
  __shared__ float pq_s[63][68];
  __shared__ float s_s[32][33];
  __shared__ float m_sm[32], l_sm[32], al_sm[32];

  int t = threadIdx.x;
  int h = blockIdx.y;
  int i0 = blockIdx.x * TI;
  int cb = h * DHEAD;

  stage_tile(&q_s[0][0], 68, qg + (size_t)i0 * HID + cb, TI, t);
  if (t < TI) { m_sm[t] = -1e30f; l_sm[t] = 0.f; }

  float o[8] = {0, 0, 0, 0, 0, 0, 0, 0};
  int i3 = t >> 3, dc = (t & 7) * 8;  // PV / store mapping: row i3, 8 d-cols
  int ip = t & 15, jp = t >> 4;       // S mapping: i in {ip, ip+16}, j in {2jp, 2jp+1}
  int ja = jp * 2, jb = ja + 1;
  int i2 = t >> 3, jj = t & 7;        // softmax mapping

  for (int jt = 0; jt < NSEQ / TJ; ++jt) {
    int j0 = jt * TJ;
    __syncthreads();
    stage_tile(&k_s[0][0], 68, kg + (size_t)j0 * HID + cb, TJ, t);
    stage_tile(&v_s[0][0], 64, vg + (size_t)j0 * HID + cb, TJ, t);
    int rbase = KREL + i0 - j0 - (TJ - 1);  // always in [1, 2047-62]
    stage_tile(&pk_s[0][0], 68, pkg + (size_t)rbase * HID + cb, WIN, t);
    stage_tile(&pq_s[0][0], 68, pqg + (size_t)rbase * HID + cb, WIN, t);
    __syncthreads();

    // ---- S tile ----
    float s00 = 0, s01 = 0, s10 = 0, s11 = 0;
    int caa = ip - ja + (TJ - 1);  // window idx for (ip, ja); (ip,jb)=caa-1; (+16,ja)=caa+16; (+16,jb)=caa+15
#pragma unroll
    for (int d = 0; d < DHEAD; d += 4) {
      float4 qa = *(float4*)&q_s[ip][d];
      float4 qb = *(float4*)&q_s[ip + 16][d];
      float4 k0 = *(float4*)&k_s[ja][d];
      float4 k1 = *(float4*)&k_s[jb][d];
      float4 pkaa = *(float4*)&pk_s[caa][d];
      float4 pkab = *(float4*)&pk_s[caa - 1][d];
      float4 pkba = *(float4*)&pk_s[caa + 16][d];
      float4 pkbb = *(float4*)&pk_s[caa + 15][d];
      float4 pqaa = *(float4*)&pq_s[caa][d];
      float4 pqab = *(float4*)&pq_s[caa - 1][d];
      float4 pqba = *(float4*)&pq_s[caa + 16][d];
      float4 pqbb = *(float4*)&pq_s[caa + 15][d];
      s00 += DOT4(qa, k0) + DOT4(qa, pkaa) + DOT4(k0, pqaa);
      s01 += DOT4(qa, k1) + DOT4(qa, pkab) + DOT4(k1, pqab);
      s10 += DOT4(qb, k0) + DOT4(qb, pkba) + DOT4(k0, pqba);
      s11 += DOT4(qb, k1) + DOT4(qb, pkbb) + DOT4(k1, pqbb);
    }
    s_s[ip][ja] = s00 * RSCALE;
    s_s[ip][jb] = s01 * RSCALE;
    s_s[ip + 16][ja] = s10 * RSCALE;
    s_s[ip + 16][jb] = s11 * RSCALE;
    __syncthreads();

    // ---- online softmax over this tile (8 lanes per row) ----
    float v0 = s_s[i2][jj], v1 = s_s[i2][jj + 8], v2 = s_s[i2][jj + 16], v3 = s_s[i2][jj + 24];
    float mx = fmaxf(fmaxf(v0, v1), fmaxf(v2, v3));
    mx = fmaxf(mx, __shfl_xor(mx, 1));
    mx = fmaxf(mx, __shfl_xor(mx, 2));
    mx = fmaxf(mx, __shfl_xor(mx, 4));
    float m_old = m_sm[i2];
    float m_new = fmaxf(m_old, mx);
    float al = __expf(m_old - m_new);
    float e0 = __expf(v0 - m_new), e1 = __expf(v1 - m_new);
    float e2 = __expf(v2 - m_new), e3 = __expf(v3 - m_new);
    s_s[i2][jj] = e0; s_s[i2][jj + 8] = e1; s_s[i2][jj + 16] = e2; s_s[i2][jj + 24] = e3;
    float ts = e0 + e1 + e2 + e3;
    ts += __shfl_xor(ts, 1);
    ts += __shfl_xor(ts, 2);
    ts += __shfl_xor(ts, 4);
    if (jj == 0) { m_sm[i2] = m_new; l_sm[i2] = l_sm[i2] * al + ts; al_sm[i2] = al; }
    __syncthreads();

    // ---- PV accumulate ----
    float al3 = al_sm[i3];
#pragma unroll
    for (int u = 0; u < 8; ++u) o[u] *= al3;
#pragma unroll 4
    for (int j = 0; j < TJ; ++j) {
      float p = s_s[i3][j];
      float4 va = *(float4*)&v_s[j][dc];
      float4 vb = *(float4*)&v_s[j][dc + 4];
      o[0] += p * va.x; o[1] += p * va.y; o[2] += p * va.z; o[3] += p * va.w;
      o[4] += p * vb.x; o[5] += p * vb.y; o[6] += p * vb.z; o[7] += p * vb.w;
    }
  }

  float linv = 1.0f / l_sm[i3];
  uint32_t p0 = (uint32_t)f2bf(o[0] * linv) | ((uint32_t)f2bf(o[1] * linv) << 16);
  uint32_t p1 = (uint32_t)f2bf(o[2] * linv) | ((uint32_t)f2bf(o[3] * linv) << 16);
  uint32_t p2 = (uint32_t)f2bf(o[4] * linv) | ((uint32_t)f2bf(o[5] * linv) << 16);
  uint32_t p3 = (uint32_t)f2bf(o[6] * linv) | ((uint32_t)f2bf(o[7] * linv) << 16);
  uint4 u; u.x = p0; u.y = p1; u.z = p2; u.w = p3;
  *(uint4*)(ctx + (size_t)(i0 + i3) * HID + cb + dc) = u;
}

// ---------------- residual + LayerNorm ----------------
__global__ __launch_bounds__(256) void ln_kernel(const float* __restrict__ xin,
                                                 const float* __restrict__ hs,
                                                 const float* __restrict__ g,
                                                 const float* __restrict__ b,
                                                 float* __restrict__ y) {
  int row = blockIdx.x, t = threadIdx.x;
  int c = t * 4;
  float4 a = *(const float4*)(xin + (size_t)row * HID + c);
  float4 hv = *(const float4*)(hs + (size_t)row * HID + c);
  float x0 = a.x + hv.x, x1 = a.y + hv.y, x2 = a.z + hv.z, x3 = a.w + hv.w;
  float s = x0 + x1 + x2 + x3;
  float sq = x0 * x0 + x1 * x1 + x2 * x2 + x3 * x3;
  for (int off = 32; off; off >>= 1) {
    s += __shfl_xor(s, off);
    sq += __shfl_xor(sq, off);
  }
  __shared__ float rs[4], rq[4];
  int w = t >> 6, lane = t & 63;
  if (lane == 0) { rs[w] = s; rq[w] = sq; }
  __syncthreads();
  s = rs[0] + rs[1] + rs[2] + rs[3];
  sq = rq[0] + rq[1] + rq[2] + rq[3];
  float mu = s * (1.0f / HID);
  float var = sq * (1.0f / HID) - mu * mu;
  float rstd = rsqrtf(var + 1e-7f);
  float4 gg = *(const float4*)(g + c);
  float4 bb = *(const float4*)(b + c);
  float4 out;
  out.x = (x0 - mu) * rstd * gg.x + bb.x;
  out.y = (x1 - mu) * rstd * gg.y + bb.y;
  out.z = (x2 - mu) * rstd * gg.z + bb.z;
  out.w = (x3 - mu) * rstd * gg.w + bb.w;
  *(float4*)(y + (size_t)row * HID + c) = out;
}

extern "C" void kernel_launch(void* const* d_in, const int* in_sizes, int n_in,
                              void* d_out, int out_size, void* d_ws, size_t ws_size,
                              hipStream_t stream) {
  const float* hs  = (const float*)d_in[0];
  const float* rel = (const float*)d_in[1];
  const float* Wq  = (const float*)d_in[2];  const float* bq  = (const float*)d_in[3];
  const float* Wk  = (const float*)d_in[4];  const float* bk  = (const float*)d_in[5];
  const float* Wv  = (const float*)d_in[6];  const float* bv  = (const float*)d_in[7];
  const float* Wpk = (const float*)d_in[8];  const float* bpk = (const float*)d_in[9];
  const float* Wpq = (const float*)d_in[10]; const float* bpq = (const float*)d_in[11];
  const float* Wo  = (const float*)d_in[12]; const float* bo  = (const float*)d_in[13];
  const float* lng = (const float*)d_in[14]; const float* lnb = (const float*)d_in[15];

  char* ws = (char*)d_ws;
  const size_t MB = 1024 * 1024;
  uint16_t* hs_bf  = (uint16_t*)(ws + 0 * MB);   // 2 MB
  uint16_t* rel_bf = (uint16_t*)(ws + 2 * MB);   // 4 MB
  uint16_t* Wq_bf  = (uint16_t*)(ws + 6 * MB);
  uint16_t* Wk_bf  = (uint16_t*)(ws + 8 * MB);
  uint16_t* Wv_bf  = (uint16_t*)(ws + 10 * MB);
  uint16_t* Wpk_bf = (uint16_t*)(ws + 12 * MB);
  uint16_t* Wpq_bf = (uint16_t*)(ws + 14 * MB);
  uint16_t* Wo_bf  = (uint16_t*)(ws + 16 * MB);
  uint16_t* q_bf   = (uint16_t*)(ws + 18 * MB);
  uint16_t* k_bf   = (uint16_t*)(ws + 20 * MB);
  uint16_t* v_bf   = (uint16_t*)(ws + 22 * MB);
  uint16_t* pk_bf  = (uint16_t*)(ws + 24 * MB);  // 4 MB
  uint16_t* pq_bf  = (uint16_t*)(ws + 28 * MB);  // 4 MB
  uint16_t* ctx_bf = (uint16_t*)(ws + 32 * MB);  // 2 MB
  float*    out_f  = (float*)   (ws + 34 * MB);  // 4 MB  -> total 38 MB

  dim3 blk(256);
  cast_kernel<<<1024, blk, 0, stream>>>(hs, hs_bf, 1024 * 1024);
  cast_kernel<<<2048, blk, 0, stream>>>(rel, rel_bf, 2048 * 1024);
  cast_kernel<<<1024, blk, 0, stream>>>(Wq, Wq_bf, 1024 * 1024);
  cast_kernel<<<1024, blk, 0, stream>>>(Wk, Wk_bf, 1024 * 1024);
  cast_kernel<<<1024, blk, 0, stream>>>(Wv, Wv_bf, 1024 * 1024);
  cast_kernel<<<1024, blk, 0, stream>>>(Wpk, Wpk_bf, 1024 * 1024);
  cast_kernel<<<1024, blk, 0, stream>>>(Wpq, Wpq_bf, 1024 * 1024);
  cast_kernel<<<1024, blk, 0, stream>>>(Wo, Wo_bf, 1024 * 1024);

  gemm_kernel<<<dim3(16, 16), blk, 0, stream>>>(hs_bf, Wq_bf, bq, q_bf, 1);
  gemm_kernel<<<dim3(16, 16), blk, 0, stream>>>(hs_bf, Wk_bf, bk, k_bf, 1);
  gemm_kernel<<<dim3(16, 16), blk, 0, stream>>>(hs_bf, Wv_bf, bv, v_bf, 1);
  gemm_kernel<<<dim3(32, 16), blk, 0, stream>>>(rel_bf, Wpk_bf, bpk, pk_bf, 1);
  gemm_kernel<<<dim3(32, 16), blk, 0, stream>>>(rel_bf, Wpq_bf, bpq, pq_bf, 1);

  attn_kernel<<<dim3(32, 16), blk, 0, stream>>>(q_bf, k_bf, v_bf, pk_bf, pq_bf, ctx_bf);

  gemm_kernel<<<dim3(16, 16), blk, 0, stream>>>(ctx_bf, Wo_bf, bo, out_f, 0);

  ln_kernel<<<1024, blk, 0, stream>>>(out_f, hs, lng, lnb, (float*)d_out);
}

// Round 2
// 309.562 us; speedup vs baseline: 1.4998x; 1.4998x over previous
//
#include <hip/hip_runtime.h>
#include <stdint.h>

#define HID 1024
#define NSEQ 1024
#define KREL 1024
#define NHEAD 16
#define DHEAD 64

typedef __attribute__((ext_vector_type(8))) short bhalf8;
typedef __attribute__((ext_vector_type(4))) float floatx4;

__device__ inline uint16_t f2bf(float f) {
  union { float f; uint32_t u; } c; c.f = f;
  uint32_t u = c.u;
  return (uint16_t)((u + 0x7fffu + ((u >> 16) & 1u)) >> 16);
}

// ---------------- fused fp32 -> bf16 casts (8 segments, one launch) ----------------
struct Cast8 {
  const float* src[8];
  uint16_t* dst[8];
  int n[8];
};
__global__ __launch_bounds__(256) void cast8_kernel(Cast8 c) {
  int seg = blockIdx.y;
  int idx = (blockIdx.x * 256 + threadIdx.x) * 4;
  if (idx + 3 < c.n[seg]) {
    float4 v = *(const float4*)(c.src[seg] + idx);
    ushort4 o;
    o.x = f2bf(v.x); o.y = f2bf(v.y); o.z = f2bf(v.z); o.w = f2bf(v.w);
    *(ushort4*)(c.dst[seg] + idx) = o;
  }
}

// ---------------- bf16 MFMA GEMM: C = A @ W^T + bias ----------------
__global__ __launch_bounds__(256) void gemm_kernel(const uint16_t* __restrict__ A,
                                                   const uint16_t* __restrict__ Wt,
                                                   const float* __restrict__ bias,
                                                   void* __restrict__ C, int out_bf16) {
  __shared__ uint16_t a_s[64 * 40];
  __shared__ uint16_t b_s[64 * 40];
  int t = threadIdx.x;
  int i0 = blockIdx.x * 64;
  int n0 = blockIdx.y * 64;
  int lane = t & 63, w = t >> 6;
  int wm = (w >> 1) * 32, wn = (w & 1) * 32;
  int fr = lane & 15;
  int kg = (lane >> 4) * 8;

  int r = t >> 2, ch = (t & 3) * 8;
  const uint16_t* Arow = A + (size_t)(i0 + r) * HID + ch;
  const uint16_t* Brow = Wt + (size_t)(n0 + r) * HID + ch;
  uint16_t* as_dst = a_s + r * 40 + ch;
  uint16_t* bs_dst = b_s + r * 40 + ch;

  floatx4 acc00 = {0,0,0,0}, acc01 = {0,0,0,0}, acc10 = {0,0,0,0}, acc11 = {0,0,0,0};

  for (int kt = 0; kt < HID; kt += 32) {
    __syncthreads();
    *(uint4*)as_dst = *(const uint4*)(Arow + kt);
    *(uint4*)bs_dst = *(const uint4*)(Brow + kt);
    __syncthreads();
    bhalf8 a0 = *(bhalf8*)(a_s + (wm + fr) * 40 + kg);
    bhalf8 a1 = *(bhalf8*)(a_s + (wm + 16 + fr) * 40 + kg);
    bhalf8 b0 = *(bhalf8*)(b_s + (wn + fr) * 40 + kg);
    bhalf8 b1 = *(bhalf8*)(b_s + (wn + 16 + fr) * 40 + kg);
    acc00 = __builtin_amdgcn_mfma_f32_16x16x32_bf16(a0, b0, acc00, 0, 0, 0);
    acc01 = __builtin_amdgcn_mfma_f32_16x16x32_bf16(a0, b1, acc01, 0, 0, 0);
    acc10 = __builtin_amdgcn_mfma_f32_16x16x32_bf16(a1, b0, acc10, 0, 0, 0);
    acc11 = __builtin_amdgcn_mfma_f32_16x16x32_bf16(a1, b1, acc11, 0, 0, 0);
  }

  int rb0 = (lane >> 4) * 4;
  int cb0 = lane & 15;
#define EPI(ACC, SM, SN)                                                         \
  {                                                                              \
    int rowb = i0 + wm + (SM)*16 + rb0;                                          \
    int col = n0 + wn + (SN)*16 + cb0;                                           \
    float bv_ = bias[col];                                                       \
    _Pragma("unroll")                                                            \
    for (int rr = 0; rr < 4; ++rr) {                                             \
      float val = ACC[rr] + bv_;                                                 \
      if (out_bf16)                                                              \
        ((uint16_t*)C)[(size_t)(rowb + rr) * HID + col] = f2bf(val);             \
      else                                                                       \
        ((float*)C)[(size_t)(rowb + rr) * HID + col] = val;                      \
    }                                                                            \
  }
  EPI(acc00, 0, 0) EPI(acc01, 0, 1) EPI(acc10, 1, 0) EPI(acc11, 1, 1)
#undef EPI
}

// ---------------- staging: bf16 global tile -> bf16 LDS (vectorized copy) ----------------
__device__ inline void stage_bf(uint16_t* dst, int ldd, const uint16_t* src, int rows, int t) {
  int total = rows * 8;  // 8 chunks of 8 bf16 per 64-col row
  for (int c = t; c < total; c += 256) {
    int r = c >> 3, ch = (c & 7) * 8;
    *(uint4*)(dst + r * ldd + ch) = *(const uint4*)(src + (size_t)r * HID + ch);
  }
}
// window variant with row clamp (rbase+63 can be 2048 at the corner; row 63 unused)
__device__ inline void stage_win(uint16_t* dst, int ldd, const uint16_t* base, int rbase,
                                 int cb, int t) {
  for (int c = t; c < 64 * 8; c += 256) {
    int r = c >> 3, ch = (c & 7) * 8;
    int rg = rbase + r; if (rg > 2047) rg = 2047;
    *(uint4*)(dst + r * ldd + ch) = *(const uint4*)(base + (size_t)rg * HID + cb + ch);
  }
}

// ---------------- MFMA fused attention ----------------
// scores[h,i,j] = (q_i.k_j + q_i.pos_k[K+i-j] + k_j.pos_q[K+i-j]) / sqrt(192)
// block = (32 q-rows, 1 head), 4 waves; j-tiles of 32; online softmax.
// Window products C2P = Q @ PKwin^T (32x64), P2C = K @ PQwin^T (32x64) via MFMA;
// band gather r = i-j+31 in the Sqk epilogue; P -> LDS bf16 (A-layout) -> PV MFMA.
__global__ __launch_bounds__(256) void attn_kernel(const uint16_t* __restrict__ qg,
                                                   const uint16_t* __restrict__ kg,
                                                   const uint16_t* __restrict__ vg,
                                                   const uint16_t* __restrict__ pkg,
                                                   const uint16_t* __restrict__ pqg,
                                                   uint16_t* __restrict__ ctx) {
  const float RSCALE = 0.07216878364870323f;  // 1/sqrt(192)
  __shared__ uint16_t Qs[32][72];
  __shared__ uint16_t Ks[32][72];
  __shared__ uint16_t Vs[32][72];
  __shared__ uint16_t PKw[64][72];
  __shared__ uint16_t PQw[64][72];
  __shared__ float C2P[32][68];
  __shared__ float P2C[32][68];
  __shared__ float Sfp[32][36];
  __shared__ uint16_t Pbf[32][40];
  __shared__ float m_sm[32], l_sm[32], al_sm[32];

  int t = threadIdx.x;
  int lane = t & 63, w = t >> 6;
  int fm = lane & 15;   // frag row/col index
  int kq = lane >> 4;   // quad
  int h = blockIdx.y;
  int i0 = blockIdx.x * 32;
  int cb = h * DHEAD;

  stage_bf(&Qs[0][0], 72, qg + (size_t)i0 * HID + cb, 32, t);
  if (t < 32) { m_sm[t] = -1e30f; l_sm[t] = 0.f; }

  // persistent PV accumulators: wave w owns d-columns [w*16, w*16+16), both m-tiles
  floatx4 opv0 = {0,0,0,0}, opv1 = {0,0,0,0};
  int wn = w * 16;

  // Sqk subtile per wave: (mt, nt) = (w>>1, w&1)
  int smt = w >> 1, snt = w & 1;

  // softmax mapping
  int i2 = t >> 3, jj = t & 7;

  for (int jt = 0; jt < NSEQ / 32; ++jt) {
    int j0 = jt * 32;
    __syncthreads();
    stage_bf(&Ks[0][0], 72, kg + (size_t)j0 * HID + cb, 32, t);
    stage_bf(&Vs[0][0], 72, vg + (size_t)j0 * HID + cb, 32, t);
    int rbase = KREL + i0 - j0 - 31;
    stage_win(&PKw[0][0], 72, pkg, rbase, cb, t);
    stage_win(&PQw[0][0], 72, pqg, rbase, cb, t);
    __syncthreads();

    // ---- stage 1: window GEMMs (waves 0,1: C2P; waves 2,3: P2C) + Sqk frag ----
    {
      const uint16_t* Asrc = (w < 2) ? &Qs[0][0] : &Ks[0][0];
      const uint16_t* Bsrc = (w < 2) ? &PKw[0][0] : &PQw[0][0];
      float* Cdst = (w < 2) ? &C2P[0][0] : &P2C[0][0];
      int ntb = (w & 1) * 2;
#pragma unroll
      for (int mt = 0; mt < 2; ++mt) {
        bhalf8 a0 = *(bhalf8*)(Asrc + (mt * 16 + fm) * 72 + kq * 8);
        bhalf8 a1 = *(bhalf8*)(Asrc + (mt * 16 + fm) * 72 + kq * 8 + 32);
#pragma unroll
        for (int nt = ntb; nt < ntb + 2; ++nt) {
          bhalf8 b0 = *(bhalf8*)(Bsrc + (nt * 16 + fm) * 72 + kq * 8);
          bhalf8 b1 = *(bhalf8*)(Bsrc + (nt * 16 + fm) * 72 + kq * 8 + 32);
          floatx4 acc = {0,0,0,0};
          acc = __builtin_amdgcn_mfma_f32_16x16x32_bf16(a0, b0, acc, 0, 0, 0);
          acc = __builtin_amdgcn_mfma_f32_16x16x32_bf16(a1, b1, acc, 0, 0, 0);
#pragma unroll
          for (int r = 0; r < 4; ++r)
            Cdst[(mt * 16 + kq * 4 + r) * 68 + nt * 16 + fm] = acc[r];
        }
      }
    }
    floatx4 sacc = {0,0,0,0};
    {
      bhalf8 qa0 = *(bhalf8*)(&Qs[smt * 16 + fm][kq * 8]);
      bhalf8 qa1 = *(bhalf8*)(&Qs[smt * 16 + fm][kq * 8 + 32]);
      bhalf8 kb0 = *(bhalf8*)(&Ks[snt * 16 + fm][kq * 8]);
      bhalf8 kb1 = *(bhalf8*)(&Ks[snt * 16 + fm][kq * 8 + 32]);
      sacc = __builtin_amdgcn_mfma_f32_16x16x32_bf16(qa0, kb0, sacc, 0, 0, 0);
      sacc = __builtin_amdgcn_mfma_f32_16x16x32_bf16(qa1, kb1, sacc, 0, 0, 0);
    }
    __syncthreads();

    // ---- stage 2: band gather + combine -> Sfp ----
    {
      int jloc = snt * 16 + fm;
#pragma unroll
      for (int r = 0; r < 4; ++r) {
        int iloc = smt * 16 + kq * 4 + r;
        int rr = iloc - jloc + 31;  // in [0,62]
        Sfp[iloc][jloc] = (sacc[r] + C2P[iloc][rr] + P2C[jloc][rr]) * RSCALE;
      }
    }
    __syncthreads();

    // ---- stage 3: online softmax (8 lanes per row), P -> bf16 LDS ----
    {
      float v0 = Sfp[i2][jj], v1 = Sfp[i2][jj + 8], v2 = Sfp[i2][jj + 16], v3 = Sfp[i2][jj + 24];
      float mx = fmaxf(fmaxf(v0, v1), fmaxf(v2, v3));
      mx = fmaxf(mx, __shfl_xor(mx, 1));
      mx = fmaxf(mx, __shfl_xor(mx, 2));
      mx = fmaxf(mx, __shfl_xor(mx, 4));
      float m_old = m_sm[i2];
      float m_new = fmaxf(m_old, mx);
      float al = __expf(m_old - m_new);
      float e0 = __expf(v0 - m_new), e1 = __expf(v1 - m_new);
      float e2 = __expf(v2 - m_new), e3 = __expf(v3 - m_new);
      Pbf[i2][jj] = f2bf(e0); Pbf[i2][jj + 8] = f2bf(e1);
      Pbf[i2][jj + 16] = f2bf(e2); Pbf[i2][jj + 24] = f2bf(e3);
      float ts = e0 + e1 + e2 + e3;
      ts += __shfl_xor(ts, 1);
      ts += __shfl_xor(ts, 2);
      ts += __shfl_xor(ts, 4);
      if (jj == 0) { m_sm[i2] = m_new; l_sm[i2] = l_sm[i2] * al + ts; al_sm[i2] = al; }
    }
    __syncthreads();

    // ---- stage 4: PV accumulate via MFMA ----
    {
      // rescale accumulators by per-row alpha
#pragma unroll
      for (int r = 0; r < 4; ++r) {
        opv0[r] *= al_sm[kq * 4 + r];
        opv1[r] *= al_sm[16 + kq * 4 + r];
      }
      // B-frag: V^T gather  B[n=d][k=j] = Vs[j][wn+fm]
      bhalf8 bfr;
#pragma unroll
      for (int u = 0; u < 8; ++u)
        ((short*)&bfr)[u] = (short)Vs[kq * 8 + u][wn + fm];
      bhalf8 pa0 = *(bhalf8*)(&Pbf[fm][kq * 8]);
      bhalf8 pa1 = *(bhalf8*)(&Pbf[16 + fm][kq * 8]);
      opv0 = __builtin_amdgcn_mfma_f32_16x16x32_bf16(pa0, bfr, opv0, 0, 0, 0);
      opv1 = __builtin_amdgcn_mfma_f32_16x16x32_bf16(pa1, bfr, opv1, 0, 0, 0);
    }
  }

  // ---- epilogue: O = acc / l ----
#pragma unroll
  for (int r = 0; r < 4; ++r) {
    int ia = kq * 4 + r, ib = 16 + kq * 4 + r;
    float la = 1.0f / l_sm[ia], lb = 1.0f / l_sm[ib];
    ctx[(size_t)(i0 + ia) * HID + cb + wn + fm] = f2bf(opv0[r] * la);
    ctx[(size_t)(i0 + ib) * HID + cb + wn + fm] = f2bf(opv1[r] * lb);
  }
}

// ---------------- residual + LayerNorm ----------------
__global__ __launch_bounds__(256) void ln_kernel(const float* __restrict__ xin,
                                                 const float* __restrict__ hs,
                                                 const float* __restrict__ g,
                                                 const float* __restrict__ b,
                                                 float* __restrict__ y) {
  int row = blockIdx.x, t = threadIdx.x;
  int c = t * 4;
  float4 a = *(const float4*)(xin + (size_t)row * HID + c);
  float4 hv = *(const float4*)(hs + (size_t)row * HID + c);
  float x0 = a.x + hv.x, x1 = a.y + hv.y, x2 = a.z + hv.z, x3 = a.w + hv.w;
  float s = x0 + x1 + x2 + x3;
  float sq = x0 * x0 + x1 * x1 + x2 * x2 + x3 * x3;
  for (int off = 32; off; off >>= 1) {
    s += __shfl_xor(s, off);
    sq += __shfl_xor(sq, off);
  }
  __shared__ float rs[4], rq[4];
  int w = t >> 6, lane = t & 63;
  if (lane == 0) { rs[w] = s; rq[w] = sq; }
  __syncthreads();
  s = rs[0] + rs[1] + rs[2] + rs[3];
  sq = rq[0] + rq[1] + rq[2] + rq[3];
  float mu = s * (1.0f / HID);
  float var = sq * (1.0f / HID) - mu * mu;
  float rstd = rsqrtf(var + 1e-7f);
  float4 gg = *(const float4*)(g + c);
  float4 bb = *(const float4*)(b + c);
  float4 out;
  out.x = (x0 - mu) * rstd * gg.x + bb.x;
  out.y = (x1 - mu) * rstd * gg.y + bb.y;
  out.z = (x2 - mu) * rstd * gg.z + bb.z;
  out.w = (x3 - mu) * rstd * gg.w + bb.w;
  *(float4*)(y + (size_t)row * HID + c) = out;
}

extern "C" void kernel_launch(void* const* d_in, const int* in_sizes, int n_in,
                              void* d_out, int out_size, void* d_ws, size_t ws_size,
                              hipStream_t stream) {
  const float* hs  = (const float*)d_in[0];
  const float* rel = (const float*)d_in[1];
  const float* Wq  = (const float*)d_in[2];  const float* bq  = (const float*)d_in[3];
  const float* Wk  = (const float*)d_in[4];  const float* bk  = (const float*)d_in[5];
  const float* Wv  = (const float*)d_in[6];  const float* bv  = (const float*)d_in[7];
  const float* Wpk = (const float*)d_in[8];  const float* bpk = (const float*)d_in[9];
  const float* Wpq = (const float*)d_in[10]; const float* bpq = (const float*)d_in[11];
  const float* Wo  = (const float*)d_in[12]; const float* bo  = (const float*)d_in[13];
  const float* lng = (const float*)d_in[14]; const float* lnb = (const float*)d_in[15];

  char* ws = (char*)d_ws;
  const size_t MB = 1024 * 1024;
  uint16_t* hs_bf  = (uint16_t*)(ws + 0 * MB);
  uint16_t* rel_bf = (uint16_t*)(ws + 2 * MB);
  uint16_t* Wq_bf  = (uint16_t*)(ws + 6 * MB);
  uint16_t* Wk_bf  = (uint16_t*)(ws + 8 * MB);
  uint16_t* Wv_bf  = (uint16_t*)(ws + 10 * MB);
  uint16_t* Wpk_bf = (uint16_t*)(ws + 12 * MB);
  uint16_t* Wpq_bf = (uint16_t*)(ws + 14 * MB);
  uint16_t* Wo_bf  = (uint16_t*)(ws + 16 * MB);
  uint16_t* q_bf   = (uint16_t*)(ws + 18 * MB);
  uint16_t* k_bf   = (uint16_t*)(ws + 20 * MB);
  uint16_t* v_bf   = (uint16_t*)(ws + 22 * MB);
  uint16_t* pk_bf  = (uint16_t*)(ws + 24 * MB);
  uint16_t* pq_bf  = (uint16_t*)(ws + 28 * MB);
  uint16_t* ctx_bf = (uint16_t*)(ws + 32 * MB);
  float*    out_f  = (float*)   (ws + 34 * MB);

  dim3 blk(256);
  Cast8 c8;
  c8.src[0] = hs;  c8.dst[0] = hs_bf;  c8.n[0] = 1024 * 1024;
  c8.src[1] = rel; c8.dst[1] = rel_bf; c8.n[1] = 2048 * 1024;
  c8.src[2] = Wq;  c8.dst[2] = Wq_bf;  c8.n[2] = 1024 * 1024;
  c8.src[3] = Wk;  c8.dst[3] = Wk_bf;  c8.n[3] = 1024 * 1024;
  c8.src[4] = Wv;  c8.dst[4] = Wv_bf;  c8.n[4] = 1024 * 1024;
  c8.src[5] = Wpk; c8.dst[5] = Wpk_bf; c8.n[5] = 1024 * 1024;
  c8.src[6] = Wpq; c8.dst[6] = Wpq_bf; c8.n[6] = 1024 * 1024;
  c8.src[7] = Wo;  c8.dst[7] = Wo_bf;  c8.n[7] = 1024 * 1024;
  cast8_kernel<<<dim3(2048, 8), blk, 0, stream>>>(c8);

  gemm_kernel<<<dim3(16, 16), blk, 0, stream>>>(hs_bf, Wq_bf, bq, q_bf, 1);
  gemm_kernel<<<dim3(16, 16), blk, 0, stream>>>(hs_bf, Wk_bf, bk, k_bf, 1);
  gemm_kernel<<<dim3(16, 16), blk, 0, stream>>>(hs_bf, Wv_bf, bv, v_bf, 1);
  gemm_kernel<<<dim3(32, 16), blk, 0, stream>>>(rel_bf, Wpk_bf, bpk, pk_bf, 1);
  gemm_kernel<<<dim3(32, 16), blk, 0, stream>>>(rel_bf, Wpq_bf, bpq, pq_bf, 1);

  attn_kernel<<<dim3(32, 16), blk, 0, stream>>>(q_bf, k_bf, v_bf, pk_bf, pq_bf, ctx_bf);

  gemm_kernel<<<dim3(16, 16), blk, 0, stream>>>(ctx_bf, Wo_bf, bo, out_f, 0);

  ln_kernel<<<1024, blk, 0, stream>>>(out_f, hs, lng, lnb, (float*)d_out);
}

// Round 3
// 216.464 us; speedup vs baseline: 2.1448x; 1.4301x over previous
//
#include <hip/hip_runtime.h>
#include <stdint.h>

#define HID 1024
#define NSEQ 1024
#define KREL 1024
#define NHEAD 16
#define DHEAD 64

typedef __attribute__((ext_vector_type(8))) short bhalf8;
typedef __attribute__((ext_vector_type(4))) float floatx4;

__device__ inline uint16_t f2bf(float f) {
  union { float f; uint32_t u; } c; c.f = f;
  uint32_t u = c.u;
  return (uint16_t)((u + 0x7fffu + ((u >> 16) & 1u)) >> 16);
}

// ---------------- fused fp32 -> bf16 casts ----------------
struct Cast8 {
  const float* src[8];
  uint16_t* dst[8];
  int n[8];
};
__global__ __launch_bounds__(256) void cast8_kernel(Cast8 c) {
  int seg = blockIdx.y;
  int n = c.n[seg];
  const float* s = c.src[seg];
  uint16_t* d = c.dst[seg];
  for (int idx = (blockIdx.x * 256 + threadIdx.x) * 4; idx < n; idx += 1024 * 256 * 4) {
    float4 v = *(const float4*)(s + idx);
    ushort4 o;
    o.x = f2bf(v.x); o.y = f2bf(v.y); o.z = f2bf(v.z); o.w = f2bf(v.w);
    *(ushort4*)(d + idx) = o;
  }
}

// ---------------- batched bf16 MFMA GEMM: C[z] = A @ W[z]^T + bias[z] ----------------
// 64x64 tile, BK=64, LDS double-buffer (1 barrier/slab), register prefetch.
struct GemmArgs {
  const uint16_t* A;
  const uint16_t* W[3];
  const float* bias[3];
  void* C[3];
  int out_bf16;
};
__global__ __launch_bounds__(256) void gemm_kernel(GemmArgs g) {
  __shared__ uint16_t a_s[2][64 * 72];
  __shared__ uint16_t b_s[2][64 * 72];
  int z = blockIdx.z;
  const uint16_t* A = g.A;
  const uint16_t* Wt = g.W[z];
  int t = threadIdx.x;
  int i0 = blockIdx.x * 64;
  int n0 = blockIdx.y * 64;
  int lane = t & 63, w = t >> 6;
  int wm = (w >> 1) * 32, wn = (w & 1) * 32;
  int fr = lane & 15;
  int kg = (lane >> 4) * 8;

  // staging map: thread t -> row r = t>>2, cols [(t&3)*16, +16)
  int r = t >> 2, ch = (t & 3) * 16;
  const uint16_t* Arow = A + (size_t)(i0 + r) * HID + ch;
  const uint16_t* Brow = Wt + (size_t)(n0 + r) * HID + ch;
  uint16_t* as_base = &a_s[0][0] + r * 72 + ch;
  uint16_t* bs_base = &b_s[0][0] + r * 72 + ch;

  floatx4 acc00 = {0,0,0,0}, acc01 = {0,0,0,0}, acc10 = {0,0,0,0}, acc11 = {0,0,0,0};

  uint4 ra0 = *(const uint4*)(Arow);
  uint4 ra1 = *(const uint4*)(Arow + 8);
  uint4 rb0 = *(const uint4*)(Brow);
  uint4 rb1 = *(const uint4*)(Brow + 8);
  *(uint4*)(as_base) = ra0; *(uint4*)(as_base + 8) = ra1;
  *(uint4*)(bs_base) = rb0; *(uint4*)(bs_base + 8) = rb1;

  for (int kt = 0; kt < 16; ++kt) {
    __syncthreads();
    int cur = kt & 1;
    if (kt < 15) {
      int ko = (kt + 1) * 64;
      ra0 = *(const uint4*)(Arow + ko);
      ra1 = *(const uint4*)(Arow + ko + 8);
      rb0 = *(const uint4*)(Brow + ko);
      rb1 = *(const uint4*)(Brow + ko + 8);
    }
    const uint16_t* as = &a_s[cur][0];
    const uint16_t* bs = &b_s[cur][0];
#pragma unroll
    for (int ks = 0; ks < 64; ks += 32) {
      bhalf8 a0 = *(bhalf8*)(as + (wm + fr) * 72 + ks + kg);
      bhalf8 a1 = *(bhalf8*)(as + (wm + 16 + fr) * 72 + ks + kg);
      bhalf8 b0 = *(bhalf8*)(bs + (wn + fr) * 72 + ks + kg);
      bhalf8 b1 = *(bhalf8*)(bs + (wn + 16 + fr) * 72 + ks + kg);
      acc00 = __builtin_amdgcn_mfma_f32_16x16x32_bf16(a0, b0, acc00, 0, 0, 0);
      acc01 = __builtin_amdgcn_mfma_f32_16x16x32_bf16(a0, b1, acc01, 0, 0, 0);
      acc10 = __builtin_amdgcn_mfma_f32_16x16x32_bf16(a1, b0, acc10, 0, 0, 0);
      acc11 = __builtin_amdgcn_mfma_f32_16x16x32_bf16(a1, b1, acc11, 0, 0, 0);
    }
    if (kt < 15) {
      int nxt = cur ^ 1;
      uint16_t* ad = &a_s[nxt][0] + r * 72 + ch;
      uint16_t* bd = &b_s[nxt][0] + r * 72 + ch;
      *(uint4*)(ad) = ra0; *(uint4*)(ad + 8) = ra1;
      *(uint4*)(bd) = rb0; *(uint4*)(bd + 8) = rb1;
    }
  }

  const float* bias = g.bias[z];
  void* C = g.C[z];
  int rb0i = (lane >> 4) * 4;
  int cb0 = lane & 15;
#define EPI(ACC, SM, SN)                                                         \
  {                                                                              \
    int rowb = i0 + wm + (SM)*16 + rb0i;                                         \
    int col = n0 + wn + (SN)*16 + cb0;                                           \
    float bv_ = bias[col];                                                       \
    _Pragma("unroll")                                                            \
    for (int rr = 0; rr < 4; ++rr) {                                             \
      float val = ACC[rr] + bv_;                                                 \
      if (g.out_bf16)                                                            \
        ((uint16_t*)C)[(size_t)(rowb + rr) * HID + col] = f2bf(val);             \
      else                                                                       \
        ((float*)C)[(size_t)(rowb + rr) * HID + col] = val;                      \
    }                                                                            \
  }
  EPI(acc00, 0, 0) EPI(acc01, 0, 1) EPI(acc10, 1, 0) EPI(acc11, 1, 1)
#undef EPI
}

// ---------------- MFMA fused attention, pipelined ----------------
// scores[h,i,j] = (q_i.k_j + q_i.pos_k[K+i-j] + k_j.pos_q[K+i-j]) / sqrt(192)
__global__ __launch_bounds__(256) void attn_kernel(const uint16_t* __restrict__ qg,
                                                   const uint16_t* __restrict__ kg,
                                                   const uint16_t* __restrict__ vg,
                                                   const uint16_t* __restrict__ pkg,
                                                   const uint16_t* __restrict__ pqg,
                                                   uint16_t* __restrict__ ctx) {
  const float RSCALE = 0.07216878364870323f;  // 1/sqrt(192)
  __shared__ uint16_t Qs[32][72];
  __shared__ uint16_t Ks[32][72];
  __shared__ uint16_t Vs[32][72];
  __shared__ uint16_t PKw[64][72];
  __shared__ uint16_t PQw[64][72];
  __shared__ float C2P[32][68];
  __shared__ float P2C[32][68];
  __shared__ float Sqk[32][36];
  __shared__ uint16_t Pbf[32][40];
  __shared__ float m_sm[32], l_sm[32], al_sm[32];

  int t = threadIdx.x;
  int lane = t & 63, w = t >> 6;
  int fm = lane & 15;
  int kq = lane >> 4;

  // XCD swizzle: head pairs share an XCD for K/V/pos L2 locality
  int b = blockIdx.x;
  int xcd = b & 7, slot = b >> 3;
  int h = xcd * 2 + (slot & 1);
  int i0 = (slot >> 1) * 32;
  int cb = h * DHEAD;

  // stage Q once
  for (int c = t; c < 32 * 8; c += 256) {
    int r = c >> 3, chq = (c & 7) * 8;
    *(uint4*)(&Qs[r][chq]) = *(const uint4*)(qg + (size_t)(i0 + r) * HID + cb + chq);
  }
  if (t < 32) { m_sm[t] = -1e30f; l_sm[t] = 0.f; }

  floatx4 opv0 = {0,0,0,0}, opv1 = {0,0,0,0};
  int wn = w * 16;
  int smt = w >> 1, snt = w & 1;
  int i2 = t >> 3, jj = t & 7;

  // prefetch mapping
  int pr = t >> 3, pch = (t & 7) * 8;   // K/V: row pr, cols pch..pch+7
  const uint16_t* kb = kg + cb + pch;
  const uint16_t* vb = vg + cb + pch;
  const uint16_t* pkb = pkg + cb + pch;
  const uint16_t* pqb = pqg + cb + pch;

  uint4 rk, rv, rpk0, rpk1, rpq0, rpq1;
  {
    int j0 = 0;
    int rbase = KREL + i0 - j0 - 31;
    rk = *(const uint4*)(kb + (size_t)(j0 + pr) * HID);
    rv = *(const uint4*)(vb + (size_t)(j0 + pr) * HID);
    int rg0 = rbase + pr;        // <= 1985+31 < 2048 for pr<32... pr in [0,32)
    int rg1 = rbase + pr + 32; if (rg1 > 2047) rg1 = 2047;
    rpk0 = *(const uint4*)(pkb + (size_t)rg0 * HID);
    rpk1 = *(const uint4*)(pkb + (size_t)rg1 * HID);
    rpq0 = *(const uint4*)(pqb + (size_t)rg0 * HID);
    rpq1 = *(const uint4*)(pqb + (size_t)rg1 * HID);
  }

  for (int jt = 0; jt < NSEQ / 32; ++jt) {
    __syncthreads();
    // regs -> LDS
    *(uint4*)(&Ks[pr][pch]) = rk;
    *(uint4*)(&Vs[pr][pch]) = rv;
    *(uint4*)(&PKw[pr][pch]) = rpk0;
    *(uint4*)(&PKw[pr + 32][pch]) = rpk1;
    *(uint4*)(&PQw[pr][pch]) = rpq0;
    *(uint4*)(&PQw[pr + 32][pch]) = rpq1;
    __syncthreads();

    // prefetch next j-tile
    if (jt + 1 < NSEQ / 32) {
      int j0 = (jt + 1) * 32;
      int rbase = KREL + i0 - j0 - 31;
      rk = *(const uint4*)(kb + (size_t)(j0 + pr) * HID);
      rv = *(const uint4*)(vb + (size_t)(j0 + pr) * HID);
      int rg0 = rbase + pr; if (rg0 < 0) rg0 = 0;
      int rg1 = rbase + pr + 32; if (rg1 > 2047) rg1 = 2047;
      rpk0 = *(const uint4*)(pkb + (size_t)rg0 * HID);
      rpk1 = *(const uint4*)(pkb + (size_t)rg1 * HID);
      rpq0 = *(const uint4*)(pqb + (size_t)rg0 * HID);
      rpq1 = *(const uint4*)(pqb + (size_t)rg1 * HID);
    }

    // ---- stage 1: window GEMMs + Sqk ----
    {
      const uint16_t* Asrc = (w < 2) ? &Qs[0][0] : &Ks[0][0];
      const uint16_t* Bsrc = (w < 2) ? &PKw[0][0] : &PQw[0][0];
      float* Cdst = (w < 2) ? &C2P[0][0] : &P2C[0][0];
      int ntb = (w & 1) * 2;
#pragma unroll
      for (int mt = 0; mt < 2; ++mt) {
        bhalf8 a0 = *(bhalf8*)(Asrc + (mt * 16 + fm) * 72 + kq * 8);
        bhalf8 a1 = *(bhalf8*)(Asrc + (mt * 16 + fm) * 72 + kq * 8 + 32);
#pragma unroll
        for (int nt = ntb; nt < ntb + 2; ++nt) {
          bhalf8 b0 = *(bhalf8*)(Bsrc + (nt * 16 + fm) * 72 + kq * 8);
          bhalf8 b1 = *(bhalf8*)(Bsrc + (nt * 16 + fm) * 72 + kq * 8 + 32);
          floatx4 acc = {0,0,0,0};
          acc = __builtin_amdgcn_mfma_f32_16x16x32_bf16(a0, b0, acc, 0, 0, 0);
          acc = __builtin_amdgcn_mfma_f32_16x16x32_bf16(a1, b1, acc, 0, 0, 0);
#pragma unroll
          for (int r = 0; r < 4; ++r)
            Cdst[(mt * 16 + kq * 4 + r) * 68 + nt * 16 + fm] = acc[r];
        }
      }
      bhalf8 qa0 = *(bhalf8*)(&Qs[smt * 16 + fm][kq * 8]);
      bhalf8 qa1 = *(bhalf8*)(&Qs[smt * 16 + fm][kq * 8 + 32]);
      bhalf8 kb0 = *(bhalf8*)(&Ks[snt * 16 + fm][kq * 8]);
      bhalf8 kb1 = *(bhalf8*)(&Ks[snt * 16 + fm][kq * 8 + 32]);
      floatx4 sacc = {0,0,0,0};
      sacc = __builtin_amdgcn_mfma_f32_16x16x32_bf16(qa0, kb0, sacc, 0, 0, 0);
      sacc = __builtin_amdgcn_mfma_f32_16x16x32_bf16(qa1, kb1, sacc, 0, 0, 0);
#pragma unroll
      for (int r = 0; r < 4; ++r)
        Sqk[smt * 16 + kq * 4 + r][snt * 16 + fm] = sacc[r];
    }
    __syncthreads();

    // ---- stage 2: gather + combine + online softmax ----
    {
      float sv[4];
#pragma unroll
      for (int q = 0; q < 4; ++q) {
        int j = jj + 8 * q;
        int rr = i2 - j + 31;  // in [0,62]
        sv[q] = (Sqk[i2][j] + C2P[i2][rr] + P2C[j][rr]) * RSCALE;
      }
      float mx = fmaxf(fmaxf(sv[0], sv[1]), fmaxf(sv[2], sv[3]));
      mx = fmaxf(mx, __shfl_xor(mx, 1));
      mx = fmaxf(mx, __shfl_xor(mx, 2));
      mx = fmaxf(mx, __shfl_xor(mx, 4));
      float m_old = m_sm[i2];
      float m_new = fmaxf(m_old, mx);
      float al = __expf(m_old - m_new);
      float ts = 0.f;
#pragma unroll
      for (int q = 0; q < 4; ++q) {
        float e = __expf(sv[q] - m_new);
        Pbf[i2][jj + 8 * q] = f2bf(e);
        ts += e;
      }
      ts += __shfl_xor(ts, 1);
      ts += __shfl_xor(ts, 2);
      ts += __shfl_xor(ts, 4);
      if (jj == 0) { m_sm[i2] = m_new; l_sm[i2] = l_sm[i2] * al + ts; al_sm[i2] = al; }
    }
    __syncthreads();

    // ---- stage 3: PV via MFMA ----
    {
#pragma unroll
      for (int r = 0; r < 4; ++r) {
        opv0[r] *= al_sm[kq * 4 + r];
        opv1[r] *= al_sm[16 + kq * 4 + r];
      }
      bhalf8 bfr;
#pragma unroll
      for (int u = 0; u < 8; ++u)
        ((short*)&bfr)[u] = (short)Vs[kq * 8 + u][wn + fm];
      bhalf8 pa0 = *(bhalf8*)(&Pbf[fm][kq * 8]);
      bhalf8 pa1 = *(bhalf8*)(&Pbf[16 + fm][kq * 8]);
      opv0 = __builtin_amdgcn_mfma_f32_16x16x32_bf16(pa0, bfr, opv0, 0, 0, 0);
      opv1 = __builtin_amdgcn_mfma_f32_16x16x32_bf16(pa1, bfr, opv1, 0, 0, 0);
    }
  }

#pragma unroll
  for (int r = 0; r < 4; ++r) {
    int ia = kq * 4 + r, ib = 16 + kq * 4 + r;
    float la = 1.0f / l_sm[ia], lb = 1.0f / l_sm[ib];
    ctx[(size_t)(i0 + ia) * HID + cb + wn + fm] = f2bf(opv0[r] * la);
    ctx[(size_t)(i0 + ib) * HID + cb + wn + fm] = f2bf(opv1[r] * lb);
  }
}

// ---------------- residual + LayerNorm ----------------
__global__ __launch_bounds__(256) void ln_kernel(const float* __restrict__ xin,
                                                 const float* __restrict__ hs,
                                                 const float* __restrict__ g,
                                                 const float* __restrict__ b,
                                                 float* __restrict__ y) {
  int row = blockIdx.x, t = threadIdx.x;
  int c = t * 4;
  float4 a = *(const float4*)(xin + (size_t)row * HID + c);
  float4 hv = *(const float4*)(hs + (size_t)row * HID + c);
  float x0 = a.x + hv.x, x1 = a.y + hv.y, x2 = a.z + hv.z, x3 = a.w + hv.w;
  float s = x0 + x1 + x2 + x3;
  float sq = x0 * x0 + x1 * x1 + x2 * x2 + x3 * x3;
  for (int off = 32; off; off >>= 1) {
    s += __shfl_xor(s, off);
    sq += __shfl_xor(sq, off);
  }
  __shared__ float rs[4], rq[4];
  int w = t >> 6, lane = t & 63;
  if (lane == 0) { rs[w] = s; rq[w] = sq; }
  __syncthreads();
  s = rs[0] + rs[1] + rs[2] + rs[3];
  sq = rq[0] + rq[1] + rq[2] + rq[3];
  float mu = s * (1.0f / HID);
  float var = sq * (1.0f / HID) - mu * mu;
  float rstd = rsqrtf(var + 1e-7f);
  float4 gg = *(const float4*)(g + c);
  float4 bb = *(const float4*)(b + c);
  float4 out;
  out.x = (x0 - mu) * rstd * gg.x + bb.x;
  out.y = (x1 - mu) * rstd * gg.y + bb.y;
  out.z = (x2 - mu) * rstd * gg.z + bb.z;
  out.w = (x3 - mu) * rstd * gg.w + bb.w;
  *(float4*)(y + (size_t)row * HID + c) = out;
}

extern "C" void kernel_launch(void* const* d_in, const int* in_sizes, int n_in,
                              void* d_out, int out_size, void* d_ws, size_t ws_size,
                              hipStream_t stream) {
  const float* hs  = (const float*)d_in[0];
  const float* rel = (const float*)d_in[1];
  const float* Wq  = (const float*)d_in[2];  const float* bq  = (const float*)d_in[3];
  const float* Wk  = (const float*)d_in[4];  const float* bk  = (const float*)d_in[5];
  const float* Wv  = (const float*)d_in[6];  const float* bv  = (const float*)d_in[7];
  const float* Wpk = (const float*)d_in[8];  const float* bpk = (const float*)d_in[9];
  const float* Wpq = (const float*)d_in[10]; const float* bpq = (const float*)d_in[11];
  const float* Wo  = (const float*)d_in[12]; const float* bo  = (const float*)d_in[13];
  const float* lng = (const float*)d_in[14]; const float* lnb = (const float*)d_in[15];

  char* ws = (char*)d_ws;
  const size_t MB = 1024 * 1024;
  uint16_t* hs_bf  = (uint16_t*)(ws + 0 * MB);
  uint16_t* rel_bf = (uint16_t*)(ws + 2 * MB);
  uint16_t* Wq_bf  = (uint16_t*)(ws + 6 * MB);
  uint16_t* Wk_bf  = (uint16_t*)(ws + 8 * MB);
  uint16_t* Wv_bf  = (uint16_t*)(ws + 10 * MB);
  uint16_t* Wpk_bf = (uint16_t*)(ws + 12 * MB);
  uint16_t* Wpq_bf = (uint16_t*)(ws + 14 * MB);
  uint16_t* Wo_bf  = (uint16_t*)(ws + 16 * MB);
  uint16_t* q_bf   = (uint16_t*)(ws + 18 * MB);
  uint16_t* k_bf   = (uint16_t*)(ws + 20 * MB);
  uint16_t* v_bf   = (uint16_t*)(ws + 22 * MB);
  uint16_t* pk_bf  = (uint16_t*)(ws + 24 * MB);
  uint16_t* pq_bf  = (uint16_t*)(ws + 28 * MB);
  uint16_t* ctx_bf = (uint16_t*)(ws + 32 * MB);
  float*    out_f  = (float*)   (ws + 34 * MB);

  dim3 blk(256);
  Cast8 c8;
  c8.src[0] = hs;  c8.dst[0] = hs_bf;  c8.n[0] = 1024 * 1024;
  c8.src[1] = rel; c8.dst[1] = rel_bf; c8.n[1] = 2048 * 1024;
  c8.src[2] = Wq;  c8.dst[2] = Wq_bf;  c8.n[2] = 1024 * 1024;
  c8.src[3] = Wk;  c8.dst[3] = Wk_bf;  c8.n[3] = 1024 * 1024;
  c8.src[4] = Wv;  c8.dst[4] = Wv_bf;  c8.n[4] = 1024 * 1024;
  c8.src[5] = Wpk; c8.dst[5] = Wpk_bf; c8.n[5] = 1024 * 1024;
  c8.src[6] = Wpq; c8.dst[6] = Wpq_bf; c8.n[6] = 1024 * 1024;
  c8.src[7] = Wo;  c8.dst[7] = Wo_bf;  c8.n[7] = 1024 * 1024;
  cast8_kernel<<<dim3(1024, 8), blk, 0, stream>>>(c8);

  GemmArgs gq;  // QKV batched
  gq.A = hs_bf;
  gq.W[0] = Wq_bf; gq.W[1] = Wk_bf; gq.W[2] = Wv_bf;
  gq.bias[0] = bq; gq.bias[1] = bk; gq.bias[2] = bv;
  gq.C[0] = q_bf;  gq.C[1] = k_bf;  gq.C[2] = v_bf;
  gq.out_bf16 = 1;
  gemm_kernel<<<dim3(16, 16, 3), blk, 0, stream>>>(gq);

  GemmArgs gp;  // pos_k / pos_q batched
  gp.A = rel_bf;
  gp.W[0] = Wpk_bf; gp.W[1] = Wpq_bf; gp.W[2] = nullptr;
  gp.bias[0] = bpk; gp.bias[1] = bpq; gp.bias[2] = nullptr;
  gp.C[0] = pk_bf;  gp.C[1] = pq_bf;  gp.C[2] = nullptr;
  gp.out_bf16 = 1;
  gemm_kernel<<<dim3(32, 16, 2), blk, 0, stream>>>(gp);

  attn_kernel<<<dim3(512), blk, 0, stream>>>(q_bf, k_bf, v_bf, pk_bf, pq_bf, ctx_bf);

  GemmArgs go;  // out-proj
  go.A = ctx_bf;
  go.W[0] = Wo_bf; go.W[1] = nullptr; go.W[2] = nullptr;
  go.bias[0] = bo; go.bias[1] = nullptr; go.bias[2] = nullptr;
  go.C[0] = out_f; go.C[1] = nullptr; go.C[2] = nullptr;
  go.out_bf16 = 0;
  gemm_kernel<<<dim3(16, 16, 1), blk, 0, stream>>>(go);

  ln_kernel<<<1024, blk, 0, stream>>>(out_f, hs, lng, lnb, (float*)d_out);
}